// Round 1
// baseline (143.726 us; speedup 1.0000x reference)
//
#include <hip/hip_runtime.h>
#include <math.h>

// CLUB_NCE: N=512 samples, D=400 in, H=400 hidden.
// Pipeline:
//  K1 hidden: hxT[h][n] = x @ W1x^T (transposed store), hyb[n][h] = y @ W1y^T + b1
//  K2 pair:   s(i,j) = sum_h W2[h]*relu(hyb[i,h]+hxT[h,j]) + b2 ; T=softplus(s)
//             per-(i, j-tile) partials: sum_j (1+exp(s)) [== exp(T)], sum_j T, diag T
//  K3 final:  fp64 logsumexp + means -> (lower, upper)

// ---------------- K1: hidden GEMM ----------------
// grid (8, 25, 2), block 128 (2 waves). lane = n within 64-row tile.
// wave handles 8 h-values (wave-uniform) -> W1 reads are scalar-load friendly.
__global__ __launch_bounds__(128) void club_hidden_kernel(
    const float* __restrict__ X, const float* __restrict__ Y,
    const float* __restrict__ W1, const float* __restrict__ b1,
    float* __restrict__ hxT, float* __restrict__ hyb)
{
    __shared__ float Xs[64 * 204];   // 64 n-rows x 200 k-chunk, stride 204 (quad-bank coprime)
    const int t    = threadIdx.x;
    const int lane = t & 63;
    const int wave = __builtin_amdgcn_readfirstlane(t >> 6);
    const int n0   = blockIdx.x * 64;
    const int h0   = blockIdx.y * 16 + wave * 8;      // 25*16+8+7 = 399 max, no guard needed
    const int mat  = blockIdx.z;
    const float* __restrict__ src = (mat == 0) ? X : Y;
    const int woff = (mat == 0) ? 0 : 400;

    float acc[8];
#pragma unroll
    for (int i = 0; i < 8; i++) acc[i] = 0.f;

    for (int kc = 0; kc < 400; kc += 200) {
        __syncthreads();
        // stage X[n0..n0+64)[kc..kc+200) -> Xs, coalesced float4
        for (int f4 = t; f4 < 64 * 50; f4 += 128) {
            int row = f4 / 50, kq = f4 % 50;
            float4 v = *(const float4*)(src + (size_t)(n0 + row) * 400 + kc + kq * 4);
            *(float4*)(Xs + row * 204 + kq * 4) = v;
        }
        __syncthreads();
        const float* __restrict__ wbase = W1 + (size_t)h0 * 800 + woff + kc; // wave-uniform
#pragma unroll 2
        for (int k4 = 0; k4 < 50; k4++) {
            float4 xv = *(const float4*)(Xs + lane * 204 + k4 * 4);
#pragma unroll
            for (int hh = 0; hh < 8; hh++) {
                float4 wv = *(const float4*)(wbase + hh * 800 + k4 * 4); // uniform -> s_load
                acc[hh] = fmaf(xv.x, wv.x, acc[hh]);
                acc[hh] = fmaf(xv.y, wv.y, acc[hh]);
                acc[hh] = fmaf(xv.z, wv.z, acc[hh]);
                acc[hh] = fmaf(xv.w, wv.w, acc[hh]);
            }
        }
    }
    const int n = n0 + lane;
    if (mat == 0) {
        // transposed store: consecutive lanes -> consecutive n, coalesced
#pragma unroll
        for (int hh = 0; hh < 8; hh++)
            hxT[(size_t)(h0 + hh) * 512 + n] = acc[hh];
    } else {
#pragma unroll
        for (int hh = 0; hh < 8; hh++)
            acc[hh] += b1[h0 + hh];
        *(float4*)(hyb + (size_t)n * 400 + h0)     = make_float4(acc[0], acc[1], acc[2], acc[3]);
        *(float4*)(hyb + (size_t)n * 400 + h0 + 4) = make_float4(acc[4], acc[5], acc[6], acc[7]);
    }
}

// ---------------- K2: pairwise scores + row partials ----------------
// grid (64, 8), block 128 (2 waves). lane = j within 64-col tile; wave owns 4 i-rows.
__global__ __launch_bounds__(128) void club_pair_kernel(
    const float* __restrict__ hxT, const float* __restrict__ hyb,
    const float* __restrict__ W2, const float* __restrict__ b2,
    double* __restrict__ expsum, double* __restrict__ tsum,
    double* __restrict__ diagT)
{
    __shared__ float Ls[200 * 64];   // 200 h-rows x 64 j; lane-consecutive reads: 2-way (free)
    const int t     = threadIdx.x;
    const int lane  = t & 63;
    const int wave  = __builtin_amdgcn_readfirstlane(t >> 6);
    const int ibase = blockIdx.x * 8 + wave * 4;
    const int j0    = blockIdx.y * 64;
    const int j     = j0 + lane;
    const float bb2 = b2[0];

    float acc[4] = {0.f, 0.f, 0.f, 0.f};

    for (int hc = 0; hc < 400; hc += 200) {
        __syncthreads();
        // stage hxT[hc..hc+200)[j0..j0+64) -> Ls, coalesced float4
        for (int f4 = t; f4 < 200 * 16; f4 += 128) {
            int row = f4 >> 4, jq = f4 & 15;
            float4 v = *(const float4*)(hxT + (size_t)(hc + row) * 512 + j0 + jq * 4);
            *(float4*)(Ls + row * 64 + jq * 4) = v;
        }
        __syncthreads();
#pragma unroll 2
        for (int h4 = 0; h4 < 50; h4++) {
            float bx0 = Ls[(h4 * 4 + 0) * 64 + lane];
            float bx1 = Ls[(h4 * 4 + 1) * 64 + lane];
            float bx2 = Ls[(h4 * 4 + 2) * 64 + lane];
            float bx3 = Ls[(h4 * 4 + 3) * 64 + lane];
            float4 wv = *(const float4*)(W2 + hc + h4 * 4);  // uniform -> s_load
#pragma unroll
            for (int ii = 0; ii < 4; ii++) {
                float4 av = *(const float4*)(hyb + (size_t)(ibase + ii) * 400 + hc + h4 * 4); // uniform
                float r0 = fmaxf(av.x + bx0, 0.f);
                float r1 = fmaxf(av.y + bx1, 0.f);
                float r2 = fmaxf(av.z + bx2, 0.f);
                float r3 = fmaxf(av.w + bx3, 0.f);
                acc[ii] = fmaf(r0, wv.x, acc[ii]);
                acc[ii] = fmaf(r1, wv.y, acc[ii]);
                acc[ii] = fmaf(r2, wv.z, acc[ii]);
                acc[ii] = fmaf(r3, wv.w, acc[ii]);
            }
        }
    }

    // epilogue: softplus + per-row wave reductions (fp64)
#pragma unroll
    for (int ii = 0; ii < 4; ii++) {
        const int i = ibase + ii;
        float s  = acc[ii] + bb2;
        float es = expf(s);
        float T  = log1pf(es);          // softplus(s)
        double eD = 1.0 + (double)es;   // exp(T) = 1 + exp(s), exactly
        double tD = (double)T;
        for (int off = 32; off > 0; off >>= 1) {
            eD += __shfl_down(eD, off);
            tD += __shfl_down(tD, off);
        }
        if (lane == 0) {
            expsum[i * 8 + blockIdx.y] = eD;
            tsum  [i * 8 + blockIdx.y] = tD;
        }
        if (j == i) diagT[i] = (double)T;   // T0[i] = T1[i,i]
    }
}

// ---------------- K3: final assembly ----------------
__global__ __launch_bounds__(256) void club_final_kernel(
    const double* __restrict__ expsum, const double* __restrict__ tsum,
    const double* __restrict__ diagT, float* __restrict__ out)
{
    __shared__ double sh[3 * 256];
    const int t = threadIdx.x;
    double lseS = 0.0, tS = 0.0, dS = 0.0;
    for (int i = t; i < 512; i += 256) {
        double es = 0.0, ts = 0.0;
#pragma unroll
        for (int b = 0; b < 8; b++) { es += expsum[i * 8 + b]; ts += tsum[i * 8 + b]; }
        lseS += log(es);
        tS   += ts;
        dS   += diagT[i];
    }
    sh[t] = lseS; sh[256 + t] = tS; sh[512 + t] = dS;
    __syncthreads();
    for (int off = 128; off > 0; off >>= 1) {
        if (t < off) {
            sh[t]       += sh[t + off];
            sh[256 + t] += sh[256 + t + off];
            sh[512 + t] += sh[512 + t + off];
        }
        __syncthreads();
    }
    if (t == 0) {
        double t0m  = sh[512] / 512.0;
        double lsem = sh[0]   / 512.0;
        double t1m  = sh[256] / (512.0 * 512.0);
        out[0] = (float)(t0m - (lsem - log(512.0)));   // lower bound
        out[1] = (float)(t0m - t1m);                   // upper bound
    }
}

extern "C" void kernel_launch(void* const* d_in, const int* in_sizes, int n_in,
                              void* d_out, int out_size, void* d_ws, size_t ws_size,
                              hipStream_t stream) {
    const float* X  = (const float*)d_in[0];
    const float* Y  = (const float*)d_in[1];
    const float* W1 = (const float*)d_in[2];
    const float* b1 = (const float*)d_in[3];
    const float* W2 = (const float*)d_in[4];
    const float* b2 = (const float*)d_in[5];
    float* out = (float*)d_out;

    char* ws = (char*)d_ws;
    float*  hxT    = (float*) (ws);               // 400*512*4   = 819200
    float*  hyb    = (float*) (ws + 819200);      // 512*400*4   = 819200
    double* expsum = (double*)(ws + 1638400);     // 512*8*8     = 32768
    double* tsum   = (double*)(ws + 1671168);     // 512*8*8     = 32768
    double* diagT  = (double*)(ws + 1703936);     // 512*8       = 4096
    // total ws use: ~1.71 MB

    club_hidden_kernel<<<dim3(8, 25, 2), 128, 0, stream>>>(X, Y, W1, b1, hxT, hyb);
    club_pair_kernel  <<<dim3(64, 8),    128, 0, stream>>>(hxT, hyb, W2, b2, expsum, tsum, diagT);
    club_final_kernel <<<1, 256, 0, stream>>>(expsum, tsum, diagT, out);
}

// Round 2
// 124.172 us; speedup vs baseline: 1.1575x; 1.1575x over previous
//
#include <hip/hip_runtime.h>
#include <math.h>

// CLUB_NCE: N=512, D=400, H=400.
//  K1 gemm: hxT_p[kh][h][n] = X @ W1x^T (k-half partials, transposed store)
//           hyb_p[kh][n][h] = Y @ W1y^T (+ b1 folded into kh==0 partial)
//  K2 pair: 32x32 tile GEMM-with-relu: s(i,j) = sum_h W2[h]*relu(A[i][h]+B[h][j]) + b2
//           fused softplus + per-row (over j) fp64 partial reductions
//  K3: fp64 logsumexp assembly -> (lower, upper)

#define NSAMP 512
#define DIM 400
#define HID 400

// ---------------- K1: 64x64-tile GEMM, k split in 2 across grid.z ----------------
// grid (8 n-tiles, 7 h-tiles, 4 = mat*2+khalf), block 256.
// thread: tx = t&15 -> h quad (4 h), ty = t>>4 -> n quad (4 n); 16 accs.
__global__ __launch_bounds__(256) void club_gemm_kernel(
    const float* __restrict__ X, const float* __restrict__ Y,
    const float* __restrict__ W1, const float* __restrict__ b1,
    float* __restrict__ hxT0, float* __restrict__ hxT1,
    float* __restrict__ hyb0, float* __restrict__ hyb1)
{
    __shared__ float As[64 * 41];   // [n][k] stride 41: frag-read banks 164*ty%32=4ty -> free
    __shared__ float Bs[64 * 41];   // [h][k] stride 41
    const int t  = threadIdx.x;
    const int tx = t & 15;
    const int ty = t >> 4;
    const int n0 = blockIdx.x * 64;
    const int h0 = blockIdx.y * 64;          // by=6 -> 384, guard h<400
    const int z  = blockIdx.z;
    const int mat = z >> 1, kh = z & 1;
    const float* __restrict__ src = mat ? Y : X;
    const int wcol0 = (mat ? DIM : 0) + kh * 200;  // W1 column base
    const int scol0 = kh * 200;                    // X/Y column base

    float acc[4][4];   // acc[c (h)][r (n)]
#pragma unroll
    for (int c = 0; c < 4; c++)
#pragma unroll
        for (int r = 0; r < 4; r++) acc[c][r] = 0.f;

    for (int kc = 0; kc < 200; kc += 40) {
        __syncthreads();
        // stage A: X[n0..+64)[scol0+kc..+40) -> As[n][k], coalesced f4 reads
        for (int idx = t; idx < 640; idx += 256) {
            int n = idx / 10, k4 = idx % 10;
            float4 v = *(const float4*)(src + (size_t)(n0 + n) * DIM + scol0 + kc + 4 * k4);
            float* d = As + n * 41 + 4 * k4;
            d[0] = v.x; d[1] = v.y; d[2] = v.z; d[3] = v.w;   // b32 writes (41 not 16B-aligned)
        }
        // stage B: W1[h0..+64)[wcol0+kc..+40) -> Bs[h][k] (clamp h row for by=6)
        for (int idx = t; idx < 640; idx += 256) {
            int h = idx / 10, k4 = idx % 10;
            int hrow = h0 + h; if (hrow > HID - 1) hrow = HID - 1;
            float4 v = *(const float4*)(W1 + (size_t)hrow * (2 * DIM) + wcol0 + kc + 4 * k4);
            float* d = Bs + h * 41 + 4 * k4;
            d[0] = v.x; d[1] = v.y; d[2] = v.z; d[3] = v.w;
        }
        __syncthreads();
#pragma unroll 4
        for (int k = 0; k < 40; k++) {
            float a[4], b[4];
#pragma unroll
            for (int r = 0; r < 4; r++) a[r] = As[(4 * ty + r) * 41 + k];
#pragma unroll
            for (int c = 0; c < 4; c++) b[c] = Bs[(4 * tx + c) * 41 + k];
#pragma unroll
            for (int c = 0; c < 4; c++)
#pragma unroll
                for (int r = 0; r < 4; r++)
                    acc[c][r] = fmaf(a[r], b[c], acc[c][r]);
        }
    }

    const bool hvalid = (h0 + 4 * tx) < HID;   // quad-granular: 400-384=16 = 4 quads
    if (mat == 0) {
        float* __restrict__ dst = kh ? hxT1 : hxT0;
        if (hvalid) {
#pragma unroll
            for (int c = 0; c < 4; c++) {
                int h = h0 + 4 * tx + c;
                *(float4*)(dst + (size_t)h * NSAMP + n0 + 4 * ty) =
                    make_float4(acc[c][0], acc[c][1], acc[c][2], acc[c][3]);
            }
        }
    } else {
        float* __restrict__ dst = kh ? hyb1 : hyb0;
        if (hvalid) {
            if (kh == 0) {   // fold b1 into the kh==0 partial
                float4 bv = *(const float4*)(b1 + h0 + 4 * tx);
#pragma unroll
                for (int r = 0; r < 4; r++) {
                    acc[0][r] += bv.x; acc[1][r] += bv.y;
                    acc[2][r] += bv.z; acc[3][r] += bv.w;
                }
            }
#pragma unroll
            for (int r = 0; r < 4; r++) {
                int n = n0 + 4 * ty + r;
                *(float4*)(dst + (size_t)n * HID + h0 + 4 * tx) =
                    make_float4(acc[0][r], acc[1][r], acc[2][r], acc[3][r]);
            }
        }
    }
}

// ---------------- K2: 32x32 pair tile, full h in-block, fused softplus+reduce ----------------
// grid (16 i-tiles, 16 j-tiles), block 256. tx = t&15 -> j pair, ty = t>>4 -> i pair.
__global__ __launch_bounds__(256) void club_pair_kernel(
    const float* __restrict__ hxT0, const float* __restrict__ hxT1,
    const float* __restrict__ hyb0, const float* __restrict__ hyb1,
    const float* __restrict__ W2, const float* __restrict__ b2,
    double* __restrict__ expsum, double* __restrict__ tsum,
    double* __restrict__ diagT)
{
    __shared__ float As[32 * 102];  // [i][h] stride 102: frag banks 204*ty%32=12ty -> free
    __shared__ float Bs[100 * 32];  // [h][j] stride 32: b64 over 2tx -> conflict-free
    __shared__ float W2s[100];
    const int t  = threadIdx.x;
    const int tx = t & 15;
    const int ty = t >> 4;
    const int i0 = blockIdx.x * 32;
    const int j0 = blockIdx.y * 32;

    float acc[2][2] = {{0.f, 0.f}, {0.f, 0.f}};   // [r (i)][c (j)]

    for (int hc = 0; hc < HID; hc += 100) {
        __syncthreads();
        // As[i][h] = hyb0 + hyb1 (b1 already in hyb0), coalesced f4 reads along h
        for (int idx = t; idx < 800; idx += 256) {
            int i = idx / 25, q = idx % 25;
            size_t off = (size_t)(i0 + i) * HID + hc + 4 * q;
            float4 v0 = *(const float4*)(hyb0 + off);
            float4 v1 = *(const float4*)(hyb1 + off);
            float* d = As + i * 102 + 4 * q;
            d[0] = v0.x + v1.x; d[1] = v0.y + v1.y; d[2] = v0.z + v1.z; d[3] = v0.w + v1.w;
        }
        // Bs[h][j] = hxT0 + hxT1, coalesced f4 along j
        for (int idx = t; idx < 800; idx += 256) {
            int h = idx >> 3, q = idx & 7;
            size_t off = (size_t)(hc + h) * NSAMP + j0 + 4 * q;
            float4 v0 = *(const float4*)(hxT0 + off);
            float4 v1 = *(const float4*)(hxT1 + off);
            *(float4*)(Bs + h * 32 + 4 * q) =
                make_float4(v0.x + v1.x, v0.y + v1.y, v0.z + v1.z, v0.w + v1.w);
        }
        if (t < 100) W2s[t] = W2[hc + t];
        __syncthreads();
#pragma unroll 4
        for (int h = 0; h < 100; h++) {
            float w  = W2s[h];
            float a0 = As[(2 * ty + 0) * 102 + h];
            float a1 = As[(2 * ty + 1) * 102 + h];
            float2 bv = *(const float2*)(Bs + h * 32 + 2 * tx);
            acc[0][0] = fmaf(fmaxf(a0 + bv.x, 0.f), w, acc[0][0]);
            acc[0][1] = fmaf(fmaxf(a0 + bv.y, 0.f), w, acc[0][1]);
            acc[1][0] = fmaf(fmaxf(a1 + bv.x, 0.f), w, acc[1][0]);
            acc[1][1] = fmaf(fmaxf(a1 + bv.y, 0.f), w, acc[1][1]);
        }
    }

    // epilogue: softplus, diag, per-row reduction over the 32 j's (held by tx lanes)
    const float bb2 = b2[0];
#pragma unroll
    for (int r = 0; r < 2; r++) {
        const int i = i0 + 2 * ty + r;
        double eD = 0.0, tD = 0.0;
#pragma unroll
        for (int c = 0; c < 2; c++) {
            const int j = j0 + 2 * tx + c;
            float s  = acc[r][c] + bb2;
            float es = expf(s);
            float T  = log1pf(es);            // softplus
            eD += 1.0 + (double)es;           // exp(T) exactly
            tD += (double)T;
            if (i == j) diagT[i] = (double)T; // T0[i]
        }
        for (int off = 1; off < 16; off <<= 1) {
            eD += __shfl_down(eD, off);
            tD += __shfl_down(tD, off);
        }
        if (tx == 0) {
            expsum[i * 16 + blockIdx.y] = eD;
            tsum  [i * 16 + blockIdx.y] = tD;
        }
    }
}

// ---------------- K3: final assembly ----------------
__global__ __launch_bounds__(512) void club_final_kernel(
    const double* __restrict__ expsum, const double* __restrict__ tsum,
    const double* __restrict__ diagT, float* __restrict__ out)
{
    __shared__ double sh[3 * 512];
    const int t = threadIdx.x;   // = i
    double es = 0.0, ts = 0.0;
#pragma unroll
    for (int b = 0; b < 16; b++) { es += expsum[t * 16 + b]; ts += tsum[t * 16 + b]; }
    sh[t] = log(es); sh[512 + t] = ts; sh[1024 + t] = diagT[t];
    __syncthreads();
    for (int off = 256; off > 0; off >>= 1) {
        if (t < off) {
            sh[t]        += sh[t + off];
            sh[512 + t]  += sh[512 + t + off];
            sh[1024 + t] += sh[1024 + t + off];
        }
        __syncthreads();
    }
    if (t == 0) {
        double t0m  = sh[1024] / 512.0;
        double lsem = sh[0]    / 512.0;
        double t1m  = sh[512]  / (512.0 * 512.0);
        out[0] = (float)(t0m - (lsem - log(512.0)));
        out[1] = (float)(t0m - t1m);
    }
}

extern "C" void kernel_launch(void* const* d_in, const int* in_sizes, int n_in,
                              void* d_out, int out_size, void* d_ws, size_t ws_size,
                              hipStream_t stream) {
    const float* X  = (const float*)d_in[0];
    const float* Y  = (const float*)d_in[1];
    const float* W1 = (const float*)d_in[2];
    const float* b1 = (const float*)d_in[3];
    const float* W2 = (const float*)d_in[4];
    const float* b2 = (const float*)d_in[5];
    float* out = (float*)d_out;

    char* ws = (char*)d_ws;
    float*  hxT0   = (float*) (ws);                 // 400*512*4 = 819200 each
    float*  hxT1   = (float*) (ws +  819200);
    float*  hyb0   = (float*) (ws + 1638400);
    float*  hyb1   = (float*) (ws + 2457600);
    double* expsum = (double*)(ws + 3276800);       // 512*16*8 = 65536
    double* tsum   = (double*)(ws + 3342336);       // 65536
    double* diagT  = (double*)(ws + 3407872);       // 4096  -> total ~3.26 MB

    club_gemm_kernel <<<dim3(8, 7, 4),  256, 0, stream>>>(X, Y, W1, b1, hxT0, hxT1, hyb0, hyb1);
    club_pair_kernel <<<dim3(16, 16),   256, 0, stream>>>(hxT0, hxT1, hyb0, hyb1, W2, b2,
                                                          expsum, tsum, diagT);
    club_final_kernel<<<1, 512, 0, stream>>>(expsum, tsum, diagT, out);
}

// Round 3
// 115.320 us; speedup vs baseline: 1.2463x; 1.0768x over previous
//
#include <hip/hip_runtime.h>
#include <math.h>

// CLUB_NCE: N=512, D=400, H=400.
//  K1 gemm: hxT_p[kh][h][n] = X @ W1x^T (k-half partials, transposed store)
//           hyb_p[kh][n][h] = Y @ W1y^T (+ b1 folded into kh==0 partial)
//           512-thr blocks -> 2 waves/SIMD for latency tolerance.
//  K2 pair: 16i x 32j tiles, 512 blocks (2 blocks/CU), h-chunks of 200,
//           s(i,j) = sum_h W2[h]*relu(A[i][h]+B[h][j]) + b2, fused softplus
//           + per-row fp64 partial reductions. W2 via uniform scalar load.
//  K3: fp64 logsumexp assembly -> (lower, upper)

#define NSAMP 512
#define DIM 400
#define HID 400

// ---------------- K1: 64x64-tile GEMM, k split in 2, block=512 ----------------
// grid (8 n-tiles, 7 h-tiles, 4 = mat*2+khalf), block 512 (8 waves).
// tx = t&15 -> h quad (4 h), ty = t>>4 (0..31) -> n pair (2 n); 8 accs.
__global__ __launch_bounds__(512) void club_gemm_kernel(
    const float* __restrict__ X, const float* __restrict__ Y,
    const float* __restrict__ W1, const float* __restrict__ b1,
    float* __restrict__ hxT0, float* __restrict__ hxT1,
    float* __restrict__ hyb0, float* __restrict__ hyb1)
{
    __shared__ float As[64 * 105];  // [n][k], stride 105: a-banks 9i distinct, free
    __shared__ float Bs[64 * 105];  // [h][k]: b-banks (4tx+9c)%32 -> 2-way (free)
    const int t  = threadIdx.x;
    const int tx = t & 15;
    const int ty = t >> 4;
    const int n0 = blockIdx.x * 64;
    const int h0 = blockIdx.y * 64;           // by=6 -> 384..447, store-guarded
    const int z  = blockIdx.z;
    const int mat = z >> 1, kh = z & 1;
    const float* __restrict__ src = mat ? Y : X;
    const int wcol0 = (mat ? DIM : 0) + kh * 200;
    const int scol0 = kh * 200;

    float acc[4][2];   // [c (h)][r (n)]
#pragma unroll
    for (int c = 0; c < 4; c++) { acc[c][0] = 0.f; acc[c][1] = 0.f; }

    for (int kc = 0; kc < 200; kc += 100) {
        __syncthreads();
        // stage A: X[n0..+64)[.. +100) -> As, coalesced f4 reads, b32 LDS writes
        for (int idx = t; idx < 1600; idx += 512) {
            int n = idx / 25, k4 = idx % 25;
            float4 v = *(const float4*)(src + (size_t)(n0 + n) * DIM + scol0 + kc + 4 * k4);
            float* d = As + n * 105 + 4 * k4;
            d[0] = v.x; d[1] = v.y; d[2] = v.z; d[3] = v.w;
        }
        // stage B: W1[h0..+64)[.. +100) -> Bs (clamp h row for edge tile)
        for (int idx = t; idx < 1600; idx += 512) {
            int h = idx / 25, k4 = idx % 25;
            int hrow = h0 + h; if (hrow > HID - 1) hrow = HID - 1;
            float4 v = *(const float4*)(W1 + (size_t)hrow * (2 * DIM) + wcol0 + kc + 4 * k4);
            float* d = Bs + h * 105 + 4 * k4;
            d[0] = v.x; d[1] = v.y; d[2] = v.z; d[3] = v.w;
        }
        __syncthreads();
#pragma unroll 4
        for (int k = 0; k < 100; k++) {
            float a0 = As[(2 * ty + 0) * 105 + k];
            float a1 = As[(2 * ty + 1) * 105 + k];
#pragma unroll
            for (int c = 0; c < 4; c++) {
                float b = Bs[(4 * tx + c) * 105 + k];
                acc[c][0] = fmaf(a0, b, acc[c][0]);
                acc[c][1] = fmaf(a1, b, acc[c][1]);
            }
        }
    }

    if ((h0 + 4 * tx) < HID) {    // quad-granular guard (only by=6 trims)
        if (mat == 0) {
            float* __restrict__ dst = kh ? hxT1 : hxT0;
#pragma unroll
            for (int c = 0; c < 4; c++) {
                int h = h0 + 4 * tx + c;
                *(float2*)(dst + (size_t)h * NSAMP + n0 + 2 * ty) =
                    make_float2(acc[c][0], acc[c][1]);
            }
        } else {
            float* __restrict__ dst = kh ? hyb1 : hyb0;
            if (kh == 0) {        // fold b1 into the kh==0 partial
                float4 bv = *(const float4*)(b1 + h0 + 4 * tx);
                acc[0][0] += bv.x; acc[0][1] += bv.x;
                acc[1][0] += bv.y; acc[1][1] += bv.y;
                acc[2][0] += bv.z; acc[2][1] += bv.z;
                acc[3][0] += bv.w; acc[3][1] += bv.w;
            }
#pragma unroll
            for (int r = 0; r < 2; r++) {
                int n = n0 + 2 * ty + r;
                *(float4*)(dst + (size_t)n * HID + h0 + 4 * tx) =
                    make_float4(acc[0][r], acc[1][r], acc[2][r], acc[3][r]);
            }
        }
    }
}

// ---------------- K2: 16x32 pair tiles, 512 blocks, fused softplus+reduce ----------------
// grid (32 i-tiles, 16 j-tiles), block 256 (4 waves). tx = t&31 -> j, ty = t>>5 -> i pair.
__global__ __launch_bounds__(256) void club_pair_kernel(
    const float* __restrict__ hxT0, const float* __restrict__ hxT1,
    const float* __restrict__ hyb0, const float* __restrict__ hyb1,
    const float* __restrict__ W2, const float* __restrict__ b2,
    double* __restrict__ expsum, double* __restrict__ tsum,
    double* __restrict__ diagT)
{
    __shared__ float As[16 * 204];  // [i][h-chunk], stride 204: banks (12i+h), free
    __shared__ float Bs[200 * 32];  // [h][j]: 32 consecutive -> 2-way broadcast, free
    const int t  = threadIdx.x;
    const int tx = t & 31;
    const int ty = t >> 5;          // 0..7
    const int i0 = blockIdx.x * 16;
    const int j0 = blockIdx.y * 32;
    const int j  = j0 + tx;

    float acc[2] = {0.f, 0.f};      // 2 i-rows x 1 j

    for (int hc = 0; hc < HID; hc += 200) {
        __syncthreads();
        // As[i][h] = hyb0 + hyb1 (b1 already inside), f4 reads + aligned f4 LDS writes
        for (int idx = t; idx < 800; idx += 256) {
            int i = idx / 50, q = idx % 50;
            size_t off = (size_t)(i0 + i) * HID + hc + 4 * q;
            float4 v0 = *(const float4*)(hyb0 + off);
            float4 v1 = *(const float4*)(hyb1 + off);
            *(float4*)(As + i * 204 + 4 * q) =
                make_float4(v0.x + v1.x, v0.y + v1.y, v0.z + v1.z, v0.w + v1.w);
        }
        // Bs[h][j] = hxT0 + hxT1, f4 coalesced along j
        for (int idx = t; idx < 1600; idx += 256) {
            int h = idx >> 3, q = idx & 7;
            size_t off = (size_t)(hc + h) * NSAMP + j0 + 4 * q;
            float4 v0 = *(const float4*)(hxT0 + off);
            float4 v1 = *(const float4*)(hxT1 + off);
            *(float4*)(Bs + h * 32 + 4 * q) =
                make_float4(v0.x + v1.x, v0.y + v1.y, v0.z + v1.z, v0.w + v1.w);
        }
        __syncthreads();
        const float* __restrict__ w2p = W2 + hc;   // wave-uniform -> s_load
#pragma unroll 8
        for (int h = 0; h < 200; h++) {
            float w  = w2p[h];
            float b  = Bs[h * 32 + tx];
            float a0 = As[(2 * ty + 0) * 204 + h];
            float a1 = As[(2 * ty + 1) * 204 + h];
            acc[0] = fmaf(fmaxf(a0 + b, 0.f), w, acc[0]);
            acc[1] = fmaf(fmaxf(a1 + b, 0.f), w, acc[1]);
        }
    }

    // epilogue: softplus, diag, reduce over the 32 tx-lanes (half-wave)
    const float bb2 = b2[0];
#pragma unroll
    for (int r = 0; r < 2; r++) {
        const int i = i0 + 2 * ty + r;
        float s  = acc[r] + bb2;
        float es = expf(s);
        float T  = log1pf(es);            // softplus
        if (j == i) diagT[i] = (double)T; // T0[i]
        double eD = 1.0 + (double)es;     // exp(T) exactly
        double tD = (double)T;
        for (int off = 16; off > 0; off >>= 1) {
            eD += __shfl_down(eD, off);
            tD += __shfl_down(tD, off);
        }
        if (tx == 0) {
            expsum[i * 16 + blockIdx.y] = eD;
            tsum  [i * 16 + blockIdx.y] = tD;
        }
    }
}

// ---------------- K3: final assembly ----------------
__global__ __launch_bounds__(512) void club_final_kernel(
    const double* __restrict__ expsum, const double* __restrict__ tsum,
    const double* __restrict__ diagT, float* __restrict__ out)
{
    __shared__ double sh[3 * 512];
    const int t = threadIdx.x;   // = i
    double es = 0.0, ts = 0.0;
#pragma unroll
    for (int b = 0; b < 16; b++) { es += expsum[t * 16 + b]; ts += tsum[t * 16 + b]; }
    sh[t] = log(es); sh[512 + t] = ts; sh[1024 + t] = diagT[t];
    __syncthreads();
    for (int off = 256; off > 0; off >>= 1) {
        if (t < off) {
            sh[t]        += sh[t + off];
            sh[512 + t]  += sh[512 + t + off];
            sh[1024 + t] += sh[1024 + t + off];
        }
        __syncthreads();
    }
    if (t == 0) {
        double t0m  = sh[1024] / 512.0;
        double lsem = sh[0]    / 512.0;
        double t1m  = sh[512]  / (512.0 * 512.0);
        out[0] = (float)(t0m - (lsem - log(512.0)));
        out[1] = (float)(t0m - t1m);
    }
}

extern "C" void kernel_launch(void* const* d_in, const int* in_sizes, int n_in,
                              void* d_out, int out_size, void* d_ws, size_t ws_size,
                              hipStream_t stream) {
    const float* X  = (const float*)d_in[0];
    const float* Y  = (const float*)d_in[1];
    const float* W1 = (const float*)d_in[2];
    const float* b1 = (const float*)d_in[3];
    const float* W2 = (const float*)d_in[4];
    const float* b2 = (const float*)d_in[5];
    float* out = (float*)d_out;

    char* ws = (char*)d_ws;
    float*  hxT0   = (float*) (ws);                 // 400*512*4 = 819200 each
    float*  hxT1   = (float*) (ws +  819200);
    float*  hyb0   = (float*) (ws + 1638400);
    float*  hyb1   = (float*) (ws + 2457600);
    double* expsum = (double*)(ws + 3276800);       // 512*16*8 = 65536
    double* tsum   = (double*)(ws + 3342336);       // 65536
    double* diagT  = (double*)(ws + 3407872);       // 4096

    club_gemm_kernel <<<dim3(8, 7, 4), 512, 0, stream>>>(X, Y, W1, b1, hxT0, hxT1, hyb0, hyb1);
    club_pair_kernel <<<dim3(32, 16),  256, 0, stream>>>(hxT0, hxT1, hyb0, hyb1, W2, b2,
                                                         expsum, tsum, diagT);
    club_final_kernel<<<1, 512, 0, stream>>>(expsum, tsum, diagT, out);
}